// Round 1
// baseline (1324.634 us; speedup 1.0000x reference)
//
#include <hip/hip_runtime.h>
#include <stdint.h>

#define Nn 50000
#define Ee 800000
#define FIN 128
#define HIDD 256
#define CLSS 64
#define NCHUNK ((Nn + 255) / 256)   // 196

// ---------------- CSR build ----------------

__global__ void k_count(const int* __restrict__ ei, int* __restrict__ cnt) {
    int e = blockIdx.x * 256 + threadIdx.x;
    if (e >= Ee) return;
    int u = ei[e], p = ei[Ee + e];
    atomicAdd(&cnt[p], 1);        // cnt_p
    atomicAdd(&cnt[Nn + u], 1);   // cnt_u
}

__global__ void k_scan1(const int* __restrict__ cnt, int* __restrict__ off,
                        int* __restrict__ csum) {
    __shared__ int buf[256];
    int side = blockIdx.y;
    int i = blockIdx.x * 256 + threadIdx.x;
    int v = (i < Nn) ? cnt[side * Nn + i] : 0;
    buf[threadIdx.x] = v;
    __syncthreads();
    #pragma unroll
    for (int d = 1; d < 256; d <<= 1) {
        int t = (threadIdx.x >= d) ? buf[threadIdx.x - d] : 0;
        __syncthreads();
        buf[threadIdx.x] += t;
        __syncthreads();
    }
    if (i < Nn) off[side * Nn + i] = buf[threadIdx.x] - v;  // local exclusive
    if (threadIdx.x == 255) csum[side * NCHUNK + blockIdx.x] = buf[255];
}

__global__ void k_scan2(int* __restrict__ csum) {
    __shared__ int buf[256];
    int side = blockIdx.x;
    int v = (threadIdx.x < NCHUNK) ? csum[side * NCHUNK + threadIdx.x] : 0;
    buf[threadIdx.x] = v;
    __syncthreads();
    for (int d = 1; d < 256; d <<= 1) {
        int t = (threadIdx.x >= d) ? buf[threadIdx.x - d] : 0;
        __syncthreads();
        buf[threadIdx.x] += t;
        __syncthreads();
    }
    if (threadIdx.x < NCHUNK)
        csum[side * NCHUNK + threadIdx.x] = buf[threadIdx.x] - v;  // exclusive
}

__global__ void k_scan3(int* __restrict__ off, int* __restrict__ cur,
                        const int* __restrict__ csum) {
    int side = blockIdx.y;
    int i = blockIdx.x * 256 + threadIdx.x;
    if (i >= Nn) return;
    int o = off[side * Nn + i] + csum[side * NCHUNK + blockIdx.x];
    off[side * Nn + i] = o;
    cur[side * Nn + i] = o;
}

__global__ void k_fill(const int* __restrict__ ei, int* __restrict__ cur,
                       int* __restrict__ src_p, int* __restrict__ src_u) {
    int e = blockIdx.x * 256 + threadIdx.x;
    if (e >= Ee) return;
    int u = ei[e], p = ei[Ee + e];
    int sp = atomicAdd(&cur[p], 1);
    src_p[sp] = u;
    int su = atomicAdd(&cur[Nn + u], 1);
    src_u[su] = p;
}

// ---------------- mean aggregation ----------------
// one wave per dst node, 4 waves/block; lane covers D/64 contiguous floats

template <int D>
__global__ void k_agg(const float* __restrict__ X, const int* __restrict__ off,
                      const int* __restrict__ cnt, const int* __restrict__ src,
                      float* __restrict__ out) {
    int node = blockIdx.x * 4 + (threadIdx.x >> 6);
    if (node >= Nn) return;
    int lane = threadIdx.x & 63;
    int s = off[node], c = cnt[node];
    if constexpr (D == 128) {
        float2 acc = {0.f, 0.f};
        for (int j = 0; j < c; ++j) {
            int sr = src[s + j];
            float2 v = reinterpret_cast<const float2*>(X + (size_t)sr * D)[lane];
            acc.x += v.x; acc.y += v.y;
        }
        float inv = 1.0f / fmaxf((float)c, 1.0f);
        acc.x *= inv; acc.y *= inv;
        reinterpret_cast<float2*>(out + (size_t)node * D)[lane] = acc;
    } else {
        float4 acc = {0.f, 0.f, 0.f, 0.f};
        for (int j = 0; j < c; ++j) {
            int sr = src[s + j];
            float4 v = reinterpret_cast<const float4*>(X + (size_t)sr * D)[lane];
            acc.x += v.x; acc.y += v.y; acc.z += v.z; acc.w += v.w;
        }
        float inv = 1.0f / fmaxf((float)c, 1.0f);
        acc.x *= inv; acc.y *= inv; acc.z *= inv; acc.w *= inv;
        reinterpret_cast<float4*>(out + (size_t)node * D)[lane] = acc;
    }
}

// ---------------- fused dual GEMM ----------------
// C[n, o] = act( A1[n,:] . W1[o,:] + A2[n,:] . W2[o,:] + bias[o] )
// block: 256 thr, 64-node x 64-out tile, 4x4 per thread, K-chunk 32.

template <int K, int OUT, bool RELU>
__global__ void k_gemm(const float* __restrict__ A1, const float* __restrict__ W1,
                       const float* __restrict__ A2, const float* __restrict__ W2,
                       const float* __restrict__ bias, float* __restrict__ C) {
    __shared__ float As[32][65];
    __shared__ float Ws[32][65];
    int tid = threadIdx.x;
    int tx = tid & 15;    // out micro index
    int ty = tid >> 4;    // node micro index
    int node_base = blockIdx.x * 64;
    int out_base = blockIdx.y * 64;
    float acc[4][4] = {};
    for (int half = 0; half < 2; ++half) {
        const float* A = half ? A2 : A1;
        const float* W = half ? W2 : W1;
        for (int kc = 0; kc < K; kc += 32) {
            #pragma unroll
            for (int l = 0; l < 8; ++l) {
                int idx = tid + l * 256;          // 0..2047
                int n_ = idx >> 5, k_ = idx & 31;
                int node = node_base + n_;
                As[k_][n_] = (node < Nn) ? A[(size_t)node * K + kc + k_] : 0.0f;
                Ws[k_][n_] = W[(size_t)(out_base + n_) * K + kc + k_];
            }
            __syncthreads();
            #pragma unroll
            for (int k = 0; k < 32; ++k) {
                float a[4], w[4];
                #pragma unroll
                for (int i = 0; i < 4; ++i) a[i] = As[k][ty * 4 + i];
                #pragma unroll
                for (int j = 0; j < 4; ++j) w[j] = Ws[k][tx * 4 + j];
                #pragma unroll
                for (int i = 0; i < 4; ++i)
                    #pragma unroll
                    for (int j = 0; j < 4; ++j)
                        acc[i][j] += a[i] * w[j];
            }
            __syncthreads();
        }
    }
    #pragma unroll
    for (int i = 0; i < 4; ++i) {
        int node = node_base + ty * 4 + i;
        if (node >= Nn) continue;
        float4 r;
        #pragma unroll
        for (int j = 0; j < 4; ++j) {
            float v = acc[i][j] + bias[out_base + tx * 4 + j];
            if (RELU) v = fmaxf(v, 0.0f);
            (&r.x)[j] = v;
        }
        *reinterpret_cast<float4*>(C + (size_t)node * OUT + out_base + tx * 4) = r;
    }
}

// ---------------- launch ----------------

extern "C" void kernel_launch(void* const* d_in, const int* in_sizes, int n_in,
                              void* d_out, int out_size, void* d_ws, size_t ws_size,
                              hipStream_t stream) {
    const float* x_user    = (const float*)d_in[0];
    const float* x_product = (const float*)d_in[1];
    const int*   ei        = (const int*)d_in[2];
    const float* w_u1_l = (const float*)d_in[3];
    const float* b_u1   = (const float*)d_in[4];
    const float* w_u1_r = (const float*)d_in[5];
    const float* w_p1_l = (const float*)d_in[6];
    const float* b_p1   = (const float*)d_in[7];
    const float* w_p1_r = (const float*)d_in[8];
    const float* w_u2_l = (const float*)d_in[9];
    const float* b_u2   = (const float*)d_in[10];
    const float* w_u2_r = (const float*)d_in[11];
    const float* w_p2_l = (const float*)d_in[12];
    const float* b_p2   = (const float*)d_in[13];
    const float* w_p2_r = (const float*)d_in[14];

    float* out_u = (float*)d_out;
    float* out_p = out_u + (size_t)Nn * CLSS;

    char* w = (char*)d_ws;
    int* cnt  = (int*)w;  w += (size_t)2 * Nn * 4;
    int* off  = (int*)w;  w += (size_t)2 * Nn * 4;
    int* cur  = (int*)w;  w += (size_t)2 * Nn * 4;
    int* csum = (int*)w;  w += (size_t)2 * NCHUNK * 4;
    int* src_p = (int*)w; w += (size_t)Ee * 4;
    int* src_u = (int*)w; w += (size_t)Ee * 4;
    uintptr_t a = (uintptr_t)w; a = (a + 255) & ~(uintptr_t)255; w = (char*)a;
    float* h_u = (float*)w; w += (size_t)Nn * HIDD * 4;
    float* h_p = (float*)w; w += (size_t)Nn * HIDD * 4;
    float* mA  = (float*)w; w += (size_t)Nn * HIDD * 4;   // mean1 [N,128] / m2 [N,256], reused

    hipMemsetAsync(cnt, 0, (size_t)2 * Nn * 4, stream);
    k_count<<<(Ee + 255) / 256, 256, 0, stream>>>(ei, cnt);
    dim3 gsc(NCHUNK, 2);
    k_scan1<<<gsc, 256, 0, stream>>>(cnt, off, csum);
    k_scan2<<<2, 256, 0, stream>>>(csum);
    k_scan3<<<gsc, 256, 0, stream>>>(off, cur, csum);
    k_fill<<<(Ee + 255) / 256, 256, 0, stream>>>(ei, cur, src_p, src_u);

    int aggGrid = (Nn + 3) / 4;
    dim3 g1((Nn + 63) / 64, HIDD / 64);
    dim3 g2((Nn + 63) / 64, CLSS / 64);

    // layer 1, user output (dst = p-side aggregation of x_user)
    k_agg<128><<<aggGrid, 256, 0, stream>>>(x_user, off, cnt, src_p, mA);
    k_gemm<128, HIDD, true><<<g1, 256, 0, stream>>>(mA, w_u1_l, x_product, w_u1_r, b_u1, h_u);
    // layer 1, product output (dst = u-side aggregation of x_product)
    k_agg<128><<<aggGrid, 256, 0, stream>>>(x_product, off + Nn, cnt + Nn, src_u, mA);
    k_gemm<128, HIDD, true><<<g1, 256, 0, stream>>>(mA, w_p1_l, x_user, w_p1_r, b_p1, h_p);
    // layer 2, user output
    k_agg<256><<<aggGrid, 256, 0, stream>>>(h_u, off, cnt, src_p, mA);
    k_gemm<256, CLSS, false><<<g2, 256, 0, stream>>>(mA, w_u2_l, h_p, w_u2_r, b_u2, out_u);
    // layer 2, product output
    k_agg<256><<<aggGrid, 256, 0, stream>>>(h_p, off + Nn, cnt + Nn, src_u, mA);
    k_gemm<256, CLSS, false><<<g2, 256, 0, stream>>>(mA, w_p2_l, h_u, w_p2_r, b_p2, out_p);
}

// Round 2
// 435.358 us; speedup vs baseline: 3.0426x; 3.0426x over previous
//
#include <hip/hip_runtime.h>
#include <stdint.h>

#define Nn 50000
#define Ee 800000
#define FIN 128
#define HIDD 256
#define CLSS 64
#define NCHUNK ((Nn + 255) / 256)   // 196

typedef unsigned int uint_t;
typedef unsigned short us_t;
typedef __attribute__((ext_vector_type(8))) short short8;
typedef __attribute__((ext_vector_type(4))) float f32x4;

__device__ inline float bflo(uint_t v) { union { uint_t u; float f; } c; c.u = v << 16; return c.f; }
__device__ inline float bfhi(uint_t v) { union { uint_t u; float f; } c; c.u = v & 0xffff0000u; return c.f; }
__device__ inline us_t f2bf(float f) {
    union { float f; uint_t u; } c; c.f = f;
    uint_t u = c.u;
    u += 0x7fffu + ((u >> 16) & 1u);
    return (us_t)(u >> 16);
}

// ---------------- f32 -> bf16 convert ----------------
__global__ void k_cvt(const float* __restrict__ in, us_t* __restrict__ out, int n4) {
    int i = blockIdx.x * 256 + threadIdx.x;
    int stride = gridDim.x * 256;
    for (; i < n4; i += stride) {
        float4 v = reinterpret_cast<const float4*>(in)[i];
        ushort4 o;
        o.x = f2bf(v.x); o.y = f2bf(v.y); o.z = f2bf(v.z); o.w = f2bf(v.w);
        reinterpret_cast<ushort4*>(out)[i] = o;
    }
}

// ---------------- CSR build ----------------
__global__ void k_count(const int* __restrict__ ei, int* __restrict__ cnt) {
    int e = blockIdx.x * 256 + threadIdx.x;
    if (e >= Ee) return;
    int u = ei[e], p = ei[Ee + e];
    atomicAdd(&cnt[p], 1);
    atomicAdd(&cnt[Nn + u], 1);
}

__global__ void k_scan1(const int* __restrict__ cnt, int* __restrict__ off,
                        int* __restrict__ csum) {
    __shared__ int buf[256];
    int side = blockIdx.y;
    int i = blockIdx.x * 256 + threadIdx.x;
    int v = (i < Nn) ? cnt[side * Nn + i] : 0;
    buf[threadIdx.x] = v;
    __syncthreads();
    #pragma unroll
    for (int d = 1; d < 256; d <<= 1) {
        int t = (threadIdx.x >= d) ? buf[threadIdx.x - d] : 0;
        __syncthreads();
        buf[threadIdx.x] += t;
        __syncthreads();
    }
    if (i < Nn) off[side * Nn + i] = buf[threadIdx.x] - v;
    if (threadIdx.x == 255) csum[side * NCHUNK + blockIdx.x] = buf[255];
}

__global__ void k_scan2(int* __restrict__ csum) {
    __shared__ int buf[256];
    int side = blockIdx.x;
    int v = (threadIdx.x < NCHUNK) ? csum[side * NCHUNK + threadIdx.x] : 0;
    buf[threadIdx.x] = v;
    __syncthreads();
    for (int d = 1; d < 256; d <<= 1) {
        int t = (threadIdx.x >= d) ? buf[threadIdx.x - d] : 0;
        __syncthreads();
        buf[threadIdx.x] += t;
        __syncthreads();
    }
    if (threadIdx.x < NCHUNK)
        csum[side * NCHUNK + threadIdx.x] = buf[threadIdx.x] - v;
}

__global__ void k_scan3(int* __restrict__ off, int* __restrict__ cur,
                        const int* __restrict__ csum) {
    int side = blockIdx.y;
    int i = blockIdx.x * 256 + threadIdx.x;
    if (i >= Nn) return;
    int o = off[side * Nn + i] + csum[side * NCHUNK + blockIdx.x];
    off[side * Nn + i] = o;
    cur[side * Nn + i] = o;
}

__global__ void k_fill(const int* __restrict__ ei, int* __restrict__ cur,
                       int* __restrict__ src_p, int* __restrict__ src_u) {
    int e = blockIdx.x * 256 + threadIdx.x;
    if (e >= Ee) return;
    int u = ei[e], p = ei[Ee + e];
    int sp = atomicAdd(&cur[p], 1);
    src_p[sp] = u;
    int su = atomicAdd(&cur[Nn + u], 1);
    src_u[su] = p;
}

// ---------------- layer-1 mean aggregation (bf16 in, bf16 out), D=128 ----------------
// one wave per node; lane covers 2 bf16 (one dword)
__global__ void k_agg1(const us_t* __restrict__ X, const int* __restrict__ off,
                       const int* __restrict__ cnt, const int* __restrict__ src,
                       us_t* __restrict__ out) {
    int node = blockIdx.x * 4 + (threadIdx.x >> 6);
    if (node >= Nn) return;
    int lane = threadIdx.x & 63;
    int s = off[node], c = cnt[node];
    float ax = 0.f, ay = 0.f;
    int j = 0;
    for (; j + 4 <= c; j += 4) {
        int s0 = src[s + j], s1 = src[s + j + 1], s2 = src[s + j + 2], s3 = src[s + j + 3];
        uint_t v0 = reinterpret_cast<const uint_t*>(X + (size_t)s0 * 128)[lane];
        uint_t v1 = reinterpret_cast<const uint_t*>(X + (size_t)s1 * 128)[lane];
        uint_t v2 = reinterpret_cast<const uint_t*>(X + (size_t)s2 * 128)[lane];
        uint_t v3 = reinterpret_cast<const uint_t*>(X + (size_t)s3 * 128)[lane];
        ax += bflo(v0) + bflo(v1) + bflo(v2) + bflo(v3);
        ay += bfhi(v0) + bfhi(v1) + bfhi(v2) + bfhi(v3);
    }
    for (; j < c; ++j) {
        int s0 = src[s + j];
        uint_t v0 = reinterpret_cast<const uint_t*>(X + (size_t)s0 * 128)[lane];
        ax += bflo(v0); ay += bfhi(v0);
    }
    float inv = 1.0f / fmaxf((float)c, 1.0f);
    uint_t pack = (uint_t)f2bf(ax * inv) | ((uint_t)f2bf(ay * inv) << 16);
    reinterpret_cast<uint_t*>(out + (size_t)node * 128)[lane] = pack;
}

// ---------------- layer-2 mean aggregation of transformed rows, D=64 ----------------
// 16 lanes per node (4 bf16 = 8B per lane); ADDS into existing f32 out
__global__ void k_agg2(const us_t* __restrict__ T, const int* __restrict__ off,
                       const int* __restrict__ cnt, const int* __restrict__ src,
                       float* __restrict__ out) {
    int node = blockIdx.x * 16 + (threadIdx.x >> 4);
    if (node >= Nn) return;
    int sl = threadIdx.x & 15;
    int s = off[node], c = cnt[node];
    float a0 = 0.f, a1 = 0.f, a2 = 0.f, a3 = 0.f;
    int j = 0;
    for (; j + 2 <= c; j += 2) {
        int s0 = src[s + j], s1 = src[s + j + 1];
        uint2 v0 = reinterpret_cast<const uint2*>(T + (size_t)s0 * 64)[sl];
        uint2 v1 = reinterpret_cast<const uint2*>(T + (size_t)s1 * 64)[sl];
        a0 += bflo(v0.x) + bflo(v1.x); a1 += bfhi(v0.x) + bfhi(v1.x);
        a2 += bflo(v0.y) + bflo(v1.y); a3 += bfhi(v0.y) + bfhi(v1.y);
    }
    for (; j < c; ++j) {
        int s0 = src[s + j];
        uint2 v0 = reinterpret_cast<const uint2*>(T + (size_t)s0 * 64)[sl];
        a0 += bflo(v0.x); a1 += bfhi(v0.x); a2 += bflo(v0.y); a3 += bfhi(v0.y);
    }
    float inv = 1.0f / fmaxf((float)c, 1.0f);
    float4* o = reinterpret_cast<float4*>(out + (size_t)node * 64) + sl;
    float4 p = *o;
    p.x += a0 * inv; p.y += a1 * inv; p.z += a2 * inv; p.w += a3 * inv;
    *o = p;
}

// ---------------- MFMA bf16 GEMM ----------------
// C[node][out] = act( sum_h A_h[node,:] . W_h[out,:] + bias[out] )
// block 256 thr = 4 waves (2x2), tile BM=64 x BN, wave tile 32 x BN/2.
// LDS staged via global_load_lds w16, XOR-swizzled (kslot ^ row&7) so the
// stride-2*K fragment reads spread across banks (2-way max).
template <int K, int NH, int OUT, int BN, bool RELU, bool BF16OUT, bool BIAS>
__global__ __launch_bounds__(256) void k_mm(
    const us_t* __restrict__ A0, const us_t* __restrict__ W0,
    const us_t* __restrict__ A1, const us_t* __restrict__ W1,
    const float* __restrict__ bias, void* __restrict__ Cout) {
    constexpr int KSLOT = K / 8;          // 16B slots per row
    constexpr int FN = BN / 32;
    __shared__ us_t sA[64 * K];
    __shared__ us_t sW[BN * K];
    int tid = threadIdx.x, lane = tid & 63;
    int w = tid >> 6, wr = w >> 1, wc = w & 1;
    int node_base = blockIdx.x * 64, out_base = blockIdx.y * BN;

    f32x4 acc[2][FN];
    #pragma unroll
    for (int m = 0; m < 2; ++m)
        #pragma unroll
        for (int n = 0; n < FN; ++n)
            #pragma unroll
            for (int i = 0; i < 4; ++i) acc[m][n][i] = 0.f;

    const us_t* Ap_[2] = {A0, A1};
    const us_t* Wp_[2] = {W0, W1};

    for (int h = 0; h < NH; ++h) {
        const us_t* Ap = Ap_[h];
        const us_t* Wp = Wp_[h];
        // stage A: 64 rows x K bf16
        #pragma unroll
        for (int ii = 0; ii < (64 * KSLOT) / 256; ++ii) {
            int s = ii * 256 + tid;
            int row = s / KSLOT, ks = s % KSLOT;
            int ksl = ks ^ (row & 7);
            int grow = node_base + row; if (grow >= Nn) grow = Nn - 1;
            const void* g = Ap + (size_t)grow * K + ksl * 8;
            __builtin_amdgcn_global_load_lds(
                (const __attribute__((address_space(1))) unsigned int*)g,
                (__attribute__((address_space(3))) unsigned int*)&sA[(s - lane) * 8],
                16, 0, 0);
        }
        // stage W: BN rows x K bf16
        #pragma unroll
        for (int ii = 0; ii < (BN * KSLOT) / 256; ++ii) {
            int s = ii * 256 + tid;
            int row = s / KSLOT, ks = s % KSLOT;
            int ksl = ks ^ (row & 7);
            const void* g = Wp + (size_t)(out_base + row) * K + ksl * 8;
            __builtin_amdgcn_global_load_lds(
                (const __attribute__((address_space(1))) unsigned int*)g,
                (__attribute__((address_space(3))) unsigned int*)&sW[(s - lane) * 8],
                16, 0, 0);
        }
        asm volatile("s_waitcnt vmcnt(0)" ::: "memory");
        __syncthreads();

        #pragma unroll
        for (int ks = 0; ks < K / 32; ++ks) {
            short8 af[2], bf[FN];
            #pragma unroll
            for (int m = 0; m < 2; ++m) {
                int row = wr * 32 + m * 16 + (lane & 15);
                int ksl = (ks * 4 + (lane >> 4)) ^ (row & 7);
                af[m] = *reinterpret_cast<const short8*>(&sA[row * K + ksl * 8]);
            }
            #pragma unroll
            for (int n = 0; n < FN; ++n) {
                int row = wc * (BN / 2) + n * 16 + (lane & 15);
                int ksl = (ks * 4 + (lane >> 4)) ^ (row & 7);
                bf[n] = *reinterpret_cast<const short8*>(&sW[row * K + ksl * 8]);
            }
            #pragma unroll
            for (int m = 0; m < 2; ++m)
                #pragma unroll
                for (int n = 0; n < FN; ++n)
                    acc[m][n] = __builtin_amdgcn_mfma_f32_16x16x32_bf16(
                        af[m], bf[n], acc[m][n], 0, 0, 0);
        }
        if (h + 1 < NH) __syncthreads();
    }

    // epilogue: C row = node_base + wr*32 + m*16 + (lane>>4)*4 + j, col = out_base + wc*BN/2 + n*16 + (lane&15)
    #pragma unroll
    for (int n = 0; n < FN; ++n) {
        int col = out_base + wc * (BN / 2) + n * 16 + (lane & 15);
        float bv = BIAS ? bias[col] : 0.f;
        #pragma unroll
        for (int m = 0; m < 2; ++m) {
            int row0 = node_base + wr * 32 + m * 16 + ((lane >> 4) << 2);
            #pragma unroll
            for (int j = 0; j < 4; ++j) {
                int row = row0 + j;
                if (row >= Nn) continue;
                float v = acc[m][n][j] + bv;
                if (RELU) v = fmaxf(v, 0.f);
                if (BF16OUT)
                    ((us_t*)Cout)[(size_t)row * OUT + col] = f2bf(v);
                else
                    ((float*)Cout)[(size_t)row * OUT + col] = v;
            }
        }
    }
}

// ---------------- launch ----------------
extern "C" void kernel_launch(void* const* d_in, const int* in_sizes, int n_in,
                              void* d_out, int out_size, void* d_ws, size_t ws_size,
                              hipStream_t stream) {
    const float* x_user    = (const float*)d_in[0];
    const float* x_product = (const float*)d_in[1];
    const int*   ei        = (const int*)d_in[2];
    const float* w_u1_l = (const float*)d_in[3];
    const float* b_u1   = (const float*)d_in[4];
    const float* w_u1_r = (const float*)d_in[5];
    const float* w_p1_l = (const float*)d_in[6];
    const float* b_p1   = (const float*)d_in[7];
    const float* w_p1_r = (const float*)d_in[8];
    const float* w_u2_l = (const float*)d_in[9];
    const float* b_u2   = (const float*)d_in[10];
    const float* w_u2_r = (const float*)d_in[11];
    const float* w_p2_l = (const float*)d_in[12];
    const float* b_p2   = (const float*)d_in[13];
    const float* w_p2_r = (const float*)d_in[14];

    float* out_u = (float*)d_out;
    float* out_p = out_u + (size_t)Nn * CLSS;

    char* w = (char*)d_ws;
    int* cnt  = (int*)w;  w += (size_t)2 * Nn * 4;
    int* off  = (int*)w;  w += (size_t)2 * Nn * 4;
    int* cur  = (int*)w;  w += (size_t)2 * Nn * 4;
    int* csum = (int*)w;  w += (size_t)2 * NCHUNK * 4;
    int* src_p = (int*)w; w += (size_t)Ee * 4;
    int* src_u = (int*)w; w += (size_t)Ee * 4;
    uintptr_t a = (uintptr_t)w; a = (a + 255) & ~(uintptr_t)255; w = (char*)a;
    us_t* xbu  = (us_t*)w; w += (size_t)Nn * FIN * 2;
    us_t* xbp  = (us_t*)w; w += (size_t)Nn * FIN * 2;
    us_t* h_u  = (us_t*)w; w += (size_t)Nn * HIDD * 2;
    us_t* h_p  = (us_t*)w; w += (size_t)Nn * HIDD * 2;
    us_t* mean1 = (us_t*)w; w += (size_t)Nn * FIN * 2;
    us_t* tbuf = (us_t*)w; w += (size_t)Nn * CLSS * 2;
    us_t* wb_u1l = (us_t*)w; w += (size_t)HIDD * FIN * 2;
    us_t* wb_u1r = (us_t*)w; w += (size_t)HIDD * FIN * 2;
    us_t* wb_p1l = (us_t*)w; w += (size_t)HIDD * FIN * 2;
    us_t* wb_p1r = (us_t*)w; w += (size_t)HIDD * FIN * 2;
    us_t* wb_u2l = (us_t*)w; w += (size_t)CLSS * HIDD * 2;
    us_t* wb_u2r = (us_t*)w; w += (size_t)CLSS * HIDD * 2;
    us_t* wb_p2l = (us_t*)w; w += (size_t)CLSS * HIDD * 2;
    us_t* wb_p2r = (us_t*)w; w += (size_t)CLSS * HIDD * 2;

    // conversions (independent of CSR)
    auto cvt = [&](const float* src, us_t* dst, int n) {
        int n4 = n / 4;
        int blocks = (n4 + 255) / 256; if (blocks > 2048) blocks = 2048;
        k_cvt<<<blocks, 256, 0, stream>>>(src, dst, n4);
    };
    cvt(x_user, xbu, Nn * FIN);
    cvt(x_product, xbp, Nn * FIN);
    cvt(w_u1_l, wb_u1l, HIDD * FIN);
    cvt(w_u1_r, wb_u1r, HIDD * FIN);
    cvt(w_p1_l, wb_p1l, HIDD * FIN);
    cvt(w_p1_r, wb_p1r, HIDD * FIN);
    cvt(w_u2_l, wb_u2l, CLSS * HIDD);
    cvt(w_u2_r, wb_u2r, CLSS * HIDD);
    cvt(w_p2_l, wb_p2l, CLSS * HIDD);
    cvt(w_p2_r, wb_p2r, CLSS * HIDD);

    // CSR build
    hipMemsetAsync(cnt, 0, (size_t)2 * Nn * 4, stream);
    k_count<<<(Ee + 255) / 256, 256, 0, stream>>>(ei, cnt);
    dim3 gsc(NCHUNK, 2);
    k_scan1<<<gsc, 256, 0, stream>>>(cnt, off, csum);
    k_scan2<<<2, 256, 0, stream>>>(csum);
    k_scan3<<<gsc, 256, 0, stream>>>(off, cur, csum);
    k_fill<<<(Ee + 255) / 256, 256, 0, stream>>>(ei, cur, src_p, src_u);

    int agg1Grid = (Nn + 3) / 4;
    int agg2Grid = (Nn + 15) / 16;
    dim3 g1((Nn + 63) / 64, HIDD / 128);   // BN=128 -> 2 out tiles
    dim3 g2((Nn + 63) / 64, 1);            // BN=64 = OUT

    // ---- layer 1 ----
    // user side: mean_p(x_user) -> h_u = relu(mean.W_u1_l^T + x_product.W_u1_r^T + b_u1)
    k_agg1<<<agg1Grid, 256, 0, stream>>>(xbu, off, cnt, src_p, mean1);
    k_mm<FIN, 2, HIDD, 128, true, true, true><<<g1, 256, 0, stream>>>(
        mean1, wb_u1l, xbp, wb_u1r, b_u1, h_u);
    // product side
    k_agg1<<<agg1Grid, 256, 0, stream>>>(xbp, off + Nn, cnt + Nn, src_u, mean1);
    k_mm<FIN, 2, HIDD, 128, true, true, true><<<g1, 256, 0, stream>>>(
        mean1, wb_p1l, xbu, wb_p1r, b_p1, h_p);

    // ---- layer 2 (transform-then-aggregate: mean commutes with linear map) ----
    // user side: out_u = mean_p(h_u . W_u2_l^T) + h_p . W_u2_r^T + b_u2
    k_mm<HIDD, 1, CLSS, 64, false, true, false><<<g2, 256, 0, stream>>>(
        h_u, wb_u2l, nullptr, nullptr, nullptr, tbuf);
    k_mm<HIDD, 1, CLSS, 64, false, false, true><<<g2, 256, 0, stream>>>(
        h_p, wb_u2r, nullptr, nullptr, b_u2, out_u);
    k_agg2<<<agg2Grid, 256, 0, stream>>>(tbuf, off, cnt, src_p, out_u);
    // product side
    k_mm<HIDD, 1, CLSS, 64, false, true, false><<<g2, 256, 0, stream>>>(
        h_p, wb_p2l, nullptr, nullptr, nullptr, tbuf);
    k_mm<HIDD, 1, CLSS, 64, false, false, true><<<g2, 256, 0, stream>>>(
        h_u, wb_p2r, nullptr, nullptr, b_p2, out_p);
    k_agg2<<<agg2Grid, 256, 0, stream>>>(tbuf, off + Nn, cnt + Nn, src_u, out_p);
}

// Round 3
// 268.635 us; speedup vs baseline: 4.9310x; 1.6206x over previous
//
#include <hip/hip_runtime.h>
#include <stdint.h>

#define Nn 50000
#define Ee 800000
#define FIN 128
#define HIDD 256
#define CLSS 64

#define NBIN 98          // ceil(50000 / 512)
#define BSH 9            // 512 dsts per bin
#define BINSZ 512
#define BCAP 16384       // per-bin staging capacity (avg 8163, sigma ~90)
#define EPB 2048         // edges per block in k_bin
#define NEB ((Ee + EPB - 1) / EPB)   // 391

typedef unsigned int uint_t;
typedef unsigned short us_t;
typedef __attribute__((ext_vector_type(8))) short short8;
typedef __attribute__((ext_vector_type(4))) float f32x4;

__device__ inline float bflo(uint_t v) { union { uint_t u; float f; } c; c.u = v << 16; return c.f; }
__device__ inline float bfhi(uint_t v) { union { uint_t u; float f; } c; c.u = v & 0xffff0000u; return c.f; }
__device__ inline us_t f2bf(float f) {
    union { float f; uint_t u; } c; c.f = f;
    uint_t u = c.u;
    u += 0x7fffu + ((u >> 16) & 1u);
    return (us_t)(u >> 16);
}

// ---------------- f32 -> bf16 convert (big arrays) ----------------
__global__ void k_cvt(const float* __restrict__ in, us_t* __restrict__ out, int n4) {
    int i = blockIdx.x * 256 + threadIdx.x;
    int stride = gridDim.x * 256;
    for (; i < n4; i += stride) {
        float4 v = reinterpret_cast<const float4*>(in)[i];
        ushort4 o;
        o.x = f2bf(v.x); o.y = f2bf(v.y); o.z = f2bf(v.z); o.w = f2bf(v.w);
        reinterpret_cast<ushort4*>(out)[i] = o;
    }
}

// ---------------- merged weight convert (8 small arrays, one launch) ----------------
// w1..w4: HIDD*FIN = 32768 elems (8192 vec4) each; w5..w8: CLSS*HIDD = 16384 (4096 vec4).
__global__ void k_cvtw(const float* __restrict__ w1, const float* __restrict__ w2,
                       const float* __restrict__ w3, const float* __restrict__ w4,
                       const float* __restrict__ w5, const float* __restrict__ w6,
                       const float* __restrict__ w7, const float* __restrict__ w8,
                       us_t* __restrict__ o1, us_t* __restrict__ o2,
                       us_t* __restrict__ o3, us_t* __restrict__ o4,
                       us_t* __restrict__ o5, us_t* __restrict__ o6,
                       us_t* __restrict__ o7, us_t* __restrict__ o8) {
    int i = blockIdx.x * 256 + threadIdx.x;   // 0..49151
    const float* wp; us_t* op; int loc;
    if (i < 32768) {
        int seg = i >> 13; loc = i & 8191;
        switch (seg) {
            case 0: wp = w1; op = o1; break;
            case 1: wp = w2; op = o2; break;
            case 2: wp = w3; op = o3; break;
            default: wp = w4; op = o4; break;
        }
    } else {
        int j = i - 32768;
        int seg = j >> 12; loc = j & 4095;
        switch (seg) {
            case 0: wp = w5; op = o5; break;
            case 1: wp = w6; op = o6; break;
            case 2: wp = w7; op = o7; break;
            default: wp = w8; op = o8; break;
        }
    }
    float4 v = reinterpret_cast<const float4*>(wp)[loc];
    ushort4 o;
    o.x = f2bf(v.x); o.y = f2bf(v.y); o.z = f2bf(v.z); o.w = f2bf(v.w);
    reinterpret_cast<ushort4*>(op)[loc] = o;
}

// ---------------- binned CSR build, phase 1: bin edges ----------------
// entries: (local_dst << 16) | src   (src < 65536, local_dst < 512)
__global__ __launch_bounds__(256) void k_bin(const int* __restrict__ ei,
                                             int* __restrict__ bin_cnt,     // [2][NBIN]
                                             uint_t* __restrict__ ent_p,
                                             uint_t* __restrict__ ent_u) {
    __shared__ int hist[2 * NBIN];
    __shared__ int base[2 * NBIN];
    int tid = threadIdx.x;
    int e0 = blockIdx.x * EPB;
    int n = Ee - e0; if (n > EPB) n = EPB;

    for (int i = tid; i < 2 * NBIN; i += 256) hist[i] = 0;
    __syncthreads();
    for (int i = tid; i < n; i += 256) {
        int u = ei[e0 + i], p = ei[Ee + e0 + i];
        atomicAdd(&hist[p >> BSH], 1);
        atomicAdd(&hist[NBIN + (u >> BSH)], 1);
    }
    __syncthreads();
    for (int i = tid; i < 2 * NBIN; i += 256) {
        int c = hist[i];
        base[i] = c ? atomicAdd(&bin_cnt[i], c) : 0;
    }
    __syncthreads();
    for (int i = tid; i < 2 * NBIN; i += 256) hist[i] = base[i];  // reuse as cursor
    __syncthreads();
    for (int i = tid; i < n; i += 256) {
        int u = ei[e0 + i], p = ei[Ee + e0 + i];
        int bp = p >> BSH, bu = u >> BSH;
        int rp = atomicAdd(&hist[bp], 1);
        if (rp < BCAP)
            ent_p[(size_t)bp * BCAP + rp] = ((uint_t)(p & (BINSZ - 1)) << 16) | (uint_t)u;
        int ru = atomicAdd(&hist[NBIN + bu], 1);
        if (ru < BCAP)
            ent_u[(size_t)bu * BCAP + ru] = ((uint_t)(u & (BINSZ - 1)) << 16) | (uint_t)p;
    }
}

// ---------------- phase 1.5: scan bin totals -> bin CSR bases ----------------
__global__ void k_binscan(const int* __restrict__ bin_cnt, int* __restrict__ bin_base) {
    __shared__ int buf[2][128];
    int t = threadIdx.x;          // 256
    int side = t >> 7, i = t & 127;
    int v = 0;
    if (i < NBIN) { v = bin_cnt[side * NBIN + i]; if (v > BCAP) v = BCAP; }
    buf[side][i] = v;
    __syncthreads();
    #pragma unroll
    for (int d = 1; d < 128; d <<= 1) {
        int x = (i >= d) ? buf[side][i - d] : 0;
        __syncthreads();
        buf[side][i] += x;
        __syncthreads();
    }
    if (i < NBIN) bin_base[side * NBIN + i] = buf[side][i] - v;
}

// ---------------- phase 2: per-bin scatter; writes off/cnt/src ----------------
__global__ __launch_bounds__(512) void k_scatter(
    const uint_t* __restrict__ ent_p, const uint_t* __restrict__ ent_u,
    const int* __restrict__ bin_cnt, const int* __restrict__ bin_base,
    int* __restrict__ off, int* __restrict__ cnt,
    int* __restrict__ src_p, int* __restrict__ src_u) {
    __shared__ int ca[BINSZ];
    __shared__ int cb[BINSZ];
    int side = blockIdx.y, b = blockIdx.x, t = threadIdx.x;
    const uint_t* E = (side ? ent_u : ent_p) + (size_t)b * BCAP;
    int* src = side ? src_u : src_p;
    int nb = bin_cnt[side * NBIN + b]; if (nb > BCAP) nb = BCAP;
    int base = bin_base[side * NBIN + b];

    ca[t] = 0;
    __syncthreads();
    for (int i = t; i < nb; i += 512)
        atomicAdd(&ca[E[i] >> 16], 1);
    __syncthreads();
    int v = ca[t];
    // Hillis-Steele inclusive scan, double buffer
    int* A = ca; int* B = cb;
    #pragma unroll
    for (int d = 1; d < BINSZ; d <<= 1) {
        int x = A[t] + ((t >= d) ? A[t - d] : 0);
        B[t] = x;
        __syncthreads();
        int* tmp = A; A = B; B = tmp;
    }
    int excl = A[t] - v;
    B[t] = excl;   // cursors
    __syncthreads();
    for (int i = t; i < nb; i += 512) {
        uint_t e = E[i];
        int sl = atomicAdd(&B[e >> 16], 1);
        src[base + sl] = (int)(e & 0xffffu);
    }
    int d = (b << BSH) + t;
    if (d < Nn) {
        off[side * Nn + d] = base + excl;
        cnt[side * Nn + d] = v;
    }
}

// ---------------- layer-1 mean aggregation (bf16 in, bf16 out), D=128 ----------------
__global__ void k_agg1(const us_t* __restrict__ X, const int* __restrict__ off,
                       const int* __restrict__ cnt, const int* __restrict__ src,
                       us_t* __restrict__ out) {
    int node = blockIdx.x * 4 + (threadIdx.x >> 6);
    if (node >= Nn) return;
    int lane = threadIdx.x & 63;
    int s = off[node], c = cnt[node];
    float ax = 0.f, ay = 0.f;
    int j = 0;
    for (; j + 4 <= c; j += 4) {
        int s0 = src[s + j], s1 = src[s + j + 1], s2 = src[s + j + 2], s3 = src[s + j + 3];
        uint_t v0 = reinterpret_cast<const uint_t*>(X + (size_t)s0 * 128)[lane];
        uint_t v1 = reinterpret_cast<const uint_t*>(X + (size_t)s1 * 128)[lane];
        uint_t v2 = reinterpret_cast<const uint_t*>(X + (size_t)s2 * 128)[lane];
        uint_t v3 = reinterpret_cast<const uint_t*>(X + (size_t)s3 * 128)[lane];
        ax += bflo(v0) + bflo(v1) + bflo(v2) + bflo(v3);
        ay += bfhi(v0) + bfhi(v1) + bfhi(v2) + bfhi(v3);
    }
    for (; j < c; ++j) {
        int s0 = src[s + j];
        uint_t v0 = reinterpret_cast<const uint_t*>(X + (size_t)s0 * 128)[lane];
        ax += bflo(v0); ay += bfhi(v0);
    }
    float inv = 1.0f / fmaxf((float)c, 1.0f);
    uint_t pack = (uint_t)f2bf(ax * inv) | ((uint_t)f2bf(ay * inv) << 16);
    reinterpret_cast<uint_t*>(out + (size_t)node * 128)[lane] = pack;
}

// ---------------- layer-2 mean aggregation of transformed rows, D=64 ----------------
__global__ void k_agg2(const us_t* __restrict__ T, const int* __restrict__ off,
                       const int* __restrict__ cnt, const int* __restrict__ src,
                       float* __restrict__ out) {
    int node = blockIdx.x * 16 + (threadIdx.x >> 4);
    if (node >= Nn) return;
    int sl = threadIdx.x & 15;
    int s = off[node], c = cnt[node];
    float a0 = 0.f, a1 = 0.f, a2 = 0.f, a3 = 0.f;
    int j = 0;
    for (; j + 2 <= c; j += 2) {
        int s0 = src[s + j], s1 = src[s + j + 1];
        uint2 v0 = reinterpret_cast<const uint2*>(T + (size_t)s0 * 64)[sl];
        uint2 v1 = reinterpret_cast<const uint2*>(T + (size_t)s1 * 64)[sl];
        a0 += bflo(v0.x) + bflo(v1.x); a1 += bfhi(v0.x) + bfhi(v1.x);
        a2 += bflo(v0.y) + bflo(v1.y); a3 += bfhi(v0.y) + bfhi(v1.y);
    }
    for (; j < c; ++j) {
        int s0 = src[s + j];
        uint2 v0 = reinterpret_cast<const uint2*>(T + (size_t)s0 * 64)[sl];
        a0 += bflo(v0.x); a1 += bfhi(v0.x); a2 += bflo(v0.y); a3 += bfhi(v0.y);
    }
    float inv = 1.0f / fmaxf((float)c, 1.0f);
    float4* o = reinterpret_cast<float4*>(out + (size_t)node * 64) + sl;
    float4 p = *o;
    p.x += a0 * inv; p.y += a1 * inv; p.z += a2 * inv; p.w += a3 * inv;
    *o = p;
}

// ---------------- MFMA bf16 GEMM ----------------
template <int K, int NH, int OUT, int BN, bool RELU, bool BF16OUT, bool BIAS>
__global__ __launch_bounds__(256) void k_mm(
    const us_t* __restrict__ A0, const us_t* __restrict__ W0,
    const us_t* __restrict__ A1, const us_t* __restrict__ W1,
    const float* __restrict__ bias, void* __restrict__ Cout) {
    constexpr int KSLOT = K / 8;
    constexpr int FN = BN / 32;
    __shared__ us_t sA[64 * K];
    __shared__ us_t sW[BN * K];
    int tid = threadIdx.x, lane = tid & 63;
    int w = tid >> 6, wr = w >> 1, wc = w & 1;
    int node_base = blockIdx.x * 64, out_base = blockIdx.y * BN;

    f32x4 acc[2][FN];
    #pragma unroll
    for (int m = 0; m < 2; ++m)
        #pragma unroll
        for (int n = 0; n < FN; ++n)
            #pragma unroll
            for (int i = 0; i < 4; ++i) acc[m][n][i] = 0.f;

    const us_t* Ap_[2] = {A0, A1};
    const us_t* Wp_[2] = {W0, W1};

    for (int h = 0; h < NH; ++h) {
        const us_t* Ap = Ap_[h];
        const us_t* Wp = Wp_[h];
        #pragma unroll
        for (int ii = 0; ii < (64 * KSLOT) / 256; ++ii) {
            int s = ii * 256 + tid;
            int row = s / KSLOT, ks = s % KSLOT;
            int ksl = ks ^ (row & 7);
            int grow = node_base + row; if (grow >= Nn) grow = Nn - 1;
            const void* g = Ap + (size_t)grow * K + ksl * 8;
            __builtin_amdgcn_global_load_lds(
                (const __attribute__((address_space(1))) unsigned int*)g,
                (__attribute__((address_space(3))) unsigned int*)&sA[(s - lane) * 8],
                16, 0, 0);
        }
        #pragma unroll
        for (int ii = 0; ii < (BN * KSLOT) / 256; ++ii) {
            int s = ii * 256 + tid;
            int row = s / KSLOT, ks = s % KSLOT;
            int ksl = ks ^ (row & 7);
            const void* g = Wp + (size_t)(out_base + row) * K + ksl * 8;
            __builtin_amdgcn_global_load_lds(
                (const __attribute__((address_space(1))) unsigned int*)g,
                (__attribute__((address_space(3))) unsigned int*)&sW[(s - lane) * 8],
                16, 0, 0);
        }
        asm volatile("s_waitcnt vmcnt(0)" ::: "memory");
        __syncthreads();

        #pragma unroll
        for (int ks = 0; ks < K / 32; ++ks) {
            short8 af[2], bf[FN];
            #pragma unroll
            for (int m = 0; m < 2; ++m) {
                int row = wr * 32 + m * 16 + (lane & 15);
                int ksl = (ks * 4 + (lane >> 4)) ^ (row & 7);
                af[m] = *reinterpret_cast<const short8*>(&sA[row * K + ksl * 8]);
            }
            #pragma unroll
            for (int n = 0; n < FN; ++n) {
                int row = wc * (BN / 2) + n * 16 + (lane & 15);
                int ksl = (ks * 4 + (lane >> 4)) ^ (row & 7);
                bf[n] = *reinterpret_cast<const short8*>(&sW[row * K + ksl * 8]);
            }
            #pragma unroll
            for (int m = 0; m < 2; ++m)
                #pragma unroll
                for (int n = 0; n < FN; ++n)
                    acc[m][n] = __builtin_amdgcn_mfma_f32_16x16x32_bf16(
                        af[m], bf[n], acc[m][n], 0, 0, 0);
        }
        if (h + 1 < NH) __syncthreads();
    }

    #pragma unroll
    for (int n = 0; n < FN; ++n) {
        int col = out_base + wc * (BN / 2) + n * 16 + (lane & 15);
        float bv = BIAS ? bias[col] : 0.f;
        #pragma unroll
        for (int m = 0; m < 2; ++m) {
            int row0 = node_base + wr * 32 + m * 16 + ((lane >> 4) << 2);
            #pragma unroll
            for (int j = 0; j < 4; ++j) {
                int row = row0 + j;
                if (row >= Nn) continue;
                float v = acc[m][n][j] + bv;
                if (RELU) v = fmaxf(v, 0.f);
                if (BF16OUT)
                    ((us_t*)Cout)[(size_t)row * OUT + col] = f2bf(v);
                else
                    ((float*)Cout)[(size_t)row * OUT + col] = v;
            }
        }
    }
}

// ---------------- launch ----------------
extern "C" void kernel_launch(void* const* d_in, const int* in_sizes, int n_in,
                              void* d_out, int out_size, void* d_ws, size_t ws_size,
                              hipStream_t stream) {
    const float* x_user    = (const float*)d_in[0];
    const float* x_product = (const float*)d_in[1];
    const int*   ei        = (const int*)d_in[2];
    const float* w_u1_l = (const float*)d_in[3];
    const float* b_u1   = (const float*)d_in[4];
    const float* w_u1_r = (const float*)d_in[5];
    const float* w_p1_l = (const float*)d_in[6];
    const float* b_p1   = (const float*)d_in[7];
    const float* w_p1_r = (const float*)d_in[8];
    const float* w_u2_l = (const float*)d_in[9];
    const float* b_u2   = (const float*)d_in[10];
    const float* w_u2_r = (const float*)d_in[11];
    const float* w_p2_l = (const float*)d_in[12];
    const float* b_p2   = (const float*)d_in[13];
    const float* w_p2_r = (const float*)d_in[14];

    float* out_u = (float*)d_out;
    float* out_p = out_u + (size_t)Nn * CLSS;

    char* w = (char*)d_ws;
    int* bin_cnt  = (int*)w; w += (size_t)2 * NBIN * 4;
    int* bin_base = (int*)w; w += (size_t)2 * NBIN * 4;
    int* off  = (int*)w;  w += (size_t)2 * Nn * 4;
    int* cnt  = (int*)w;  w += (size_t)2 * Nn * 4;
    int* src_p = (int*)w; w += (size_t)Ee * 4;
    int* src_u = (int*)w; w += (size_t)Ee * 4;
    uint_t* ent_p = (uint_t*)w; w += (size_t)NBIN * BCAP * 4;
    uint_t* ent_u = (uint_t*)w; w += (size_t)NBIN * BCAP * 4;
    uintptr_t a = (uintptr_t)w; a = (a + 255) & ~(uintptr_t)255; w = (char*)a;
    us_t* xbu  = (us_t*)w; w += (size_t)Nn * FIN * 2;
    us_t* xbp  = (us_t*)w; w += (size_t)Nn * FIN * 2;
    us_t* h_u  = (us_t*)w; w += (size_t)Nn * HIDD * 2;
    us_t* h_p  = (us_t*)w; w += (size_t)Nn * HIDD * 2;
    us_t* mean1 = (us_t*)w; w += (size_t)Nn * FIN * 2;
    us_t* tbuf = (us_t*)w; w += (size_t)Nn * CLSS * 2;
    us_t* wb_u1l = (us_t*)w; w += (size_t)HIDD * FIN * 2;
    us_t* wb_u1r = (us_t*)w; w += (size_t)HIDD * FIN * 2;
    us_t* wb_p1l = (us_t*)w; w += (size_t)HIDD * FIN * 2;
    us_t* wb_p1r = (us_t*)w; w += (size_t)HIDD * FIN * 2;
    us_t* wb_u2l = (us_t*)w; w += (size_t)CLSS * HIDD * 2;
    us_t* wb_u2r = (us_t*)w; w += (size_t)CLSS * HIDD * 2;
    us_t* wb_p2l = (us_t*)w; w += (size_t)CLSS * HIDD * 2;
    us_t* wb_p2r = (us_t*)w; w += (size_t)CLSS * HIDD * 2;

    // conversions
    {
        int n4 = (Nn * FIN) / 4;
        int blocks = (n4 + 255) / 256; if (blocks > 2048) blocks = 2048;
        k_cvt<<<blocks, 256, 0, stream>>>(x_user, xbu, n4);
        k_cvt<<<blocks, 256, 0, stream>>>(x_product, xbp, n4);
    }
    k_cvtw<<<192, 256, 0, stream>>>(w_u1_l, w_u1_r, w_p1_l, w_p1_r,
                                    w_u2_l, w_u2_r, w_p2_l, w_p2_r,
                                    wb_u1l, wb_u1r, wb_p1l, wb_p1r,
                                    wb_u2l, wb_u2r, wb_p2l, wb_p2r);

    // binned CSR build
    hipMemsetAsync(bin_cnt, 0, (size_t)2 * NBIN * 4, stream);
    k_bin<<<NEB, 256, 0, stream>>>(ei, bin_cnt, ent_p, ent_u);
    k_binscan<<<1, 256, 0, stream>>>(bin_cnt, bin_base);
    dim3 gsc(NBIN, 2);
    k_scatter<<<gsc, 512, 0, stream>>>(ent_p, ent_u, bin_cnt, bin_base,
                                       off, cnt, src_p, src_u);

    int agg1Grid = (Nn + 3) / 4;
    int agg2Grid = (Nn + 15) / 16;
    dim3 g1((Nn + 63) / 64, HIDD / 128);
    dim3 g2((Nn + 63) / 64, 1);

    // ---- layer 1 ----
    k_agg1<<<agg1Grid, 256, 0, stream>>>(xbu, off, cnt, src_p, mean1);
    k_mm<FIN, 2, HIDD, 128, true, true, true><<<g1, 256, 0, stream>>>(
        mean1, wb_u1l, xbp, wb_u1r, b_u1, h_u);
    k_agg1<<<agg1Grid, 256, 0, stream>>>(xbp, off + Nn, cnt + Nn, src_u, mean1);
    k_mm<FIN, 2, HIDD, 128, true, true, true><<<g1, 256, 0, stream>>>(
        mean1, wb_p1l, xbu, wb_p1r, b_p1, h_p);

    // ---- layer 2 (transform-then-aggregate) ----
    k_mm<HIDD, 1, CLSS, 64, false, true, false><<<g2, 256, 0, stream>>>(
        h_u, wb_u2l, nullptr, nullptr, nullptr, tbuf);
    k_mm<HIDD, 1, CLSS, 64, false, false, true><<<g2, 256, 0, stream>>>(
        h_p, wb_u2r, nullptr, nullptr, b_u2, out_u);
    k_agg2<<<agg2Grid, 256, 0, stream>>>(tbuf, off, cnt, src_p, out_u);
    k_mm<HIDD, 1, CLSS, 64, false, true, false><<<g2, 256, 0, stream>>>(
        h_p, wb_p2l, nullptr, nullptr, nullptr, tbuf);
    k_mm<HIDD, 1, CLSS, 64, false, false, true><<<g2, 256, 0, stream>>>(
        h_u, wb_p2r, nullptr, nullptr, b_p2, out_p);
    k_agg2<<<agg2Grid, 256, 0, stream>>>(tbuf, off + Nn, cnt + Nn, src_u, out_p);
}

// Round 4
// 239.471 us; speedup vs baseline: 5.5315x; 1.1218x over previous
//
#include <hip/hip_runtime.h>
#include <stdint.h>

#define Nn 50000
#define Ee 800000
#define FIN 128
#define HIDD 256
#define CLSS 64

#define NBIN 98          // ceil(50000 / 512)
#define BSH 9
#define BINSZ 512
#define BCAP 16384
#define EPB 2048
#define NEB ((Ee + EPB - 1) / EPB)   // 391

typedef unsigned int uint_t;
typedef unsigned short us_t;
typedef __attribute__((ext_vector_type(8))) short short8;
typedef __attribute__((ext_vector_type(4))) float f32x4;

__device__ inline float bflo(uint_t v) { union { uint_t u; float f; } c; c.u = v << 16; return c.f; }
__device__ inline float bfhi(uint_t v) { union { uint_t u; float f; } c; c.u = v & 0xffff0000u; return c.f; }
__device__ inline us_t f2bf(float f) {
    union { float f; uint_t u; } c; c.f = f;
    uint_t u = c.u;
    u += 0x7fffu + ((u >> 16) & 1u);
    return (us_t)(u >> 16);
}

// ---------------- x convert, both sides in one launch ----------------
__global__ void k_cvtx(const float* __restrict__ xu, const float* __restrict__ xp,
                       us_t* __restrict__ ou, us_t* __restrict__ op, int n4) {
    const float* in = blockIdx.y ? xp : xu;
    us_t* out = blockIdx.y ? op : ou;
    int i = blockIdx.x * 256 + threadIdx.x;
    int stride = gridDim.x * 256;
    for (; i < n4; i += stride) {
        float4 v = reinterpret_cast<const float4*>(in)[i];
        ushort4 o;
        o.x = f2bf(v.x); o.y = f2bf(v.y); o.z = f2bf(v.z); o.w = f2bf(v.w);
        reinterpret_cast<ushort4*>(out)[i] = o;
    }
}

// ---------------- weight convert + bin_cnt zero (one launch) ----------------
__global__ void k_cvtw(const float* __restrict__ w1, const float* __restrict__ w2,
                       const float* __restrict__ w3, const float* __restrict__ w4,
                       const float* __restrict__ w5, const float* __restrict__ w6,
                       const float* __restrict__ w7, const float* __restrict__ w8,
                       us_t* __restrict__ o1, us_t* __restrict__ o2,
                       us_t* __restrict__ o3, us_t* __restrict__ o4,
                       us_t* __restrict__ o5, us_t* __restrict__ o6,
                       us_t* __restrict__ o7, us_t* __restrict__ o8,
                       int* __restrict__ bin_cnt) {
    if (blockIdx.x == 192) {                       // spare block: zero bin counters
        int t = threadIdx.x;
        if (t < 2 * NBIN) bin_cnt[t] = 0;
        return;
    }
    int i = blockIdx.x * 256 + threadIdx.x;        // 0..49151
    const float* wp; us_t* op; int loc;
    if (i < 32768) {
        int seg = i >> 13; loc = i & 8191;
        switch (seg) {
            case 0: wp = w1; op = o1; break;
            case 1: wp = w2; op = o2; break;
            case 2: wp = w3; op = o3; break;
            default: wp = w4; op = o4; break;
        }
    } else {
        int j = i - 32768;
        int seg = j >> 12; loc = j & 4095;
        switch (seg) {
            case 0: wp = w5; op = o5; break;
            case 1: wp = w6; op = o6; break;
            case 2: wp = w7; op = o7; break;
            default: wp = w8; op = o8; break;
        }
    }
    float4 v = reinterpret_cast<const float4*>(wp)[loc];
    ushort4 o;
    o.x = f2bf(v.x); o.y = f2bf(v.y); o.z = f2bf(v.z); o.w = f2bf(v.w);
    reinterpret_cast<ushort4*>(op)[loc] = o;
}

// ---------------- binned CSR build ----------------
__global__ __launch_bounds__(256) void k_bin(const int* __restrict__ ei,
                                             int* __restrict__ bin_cnt,
                                             uint_t* __restrict__ ent_p,
                                             uint_t* __restrict__ ent_u) {
    __shared__ int hist[2 * NBIN];
    __shared__ int base[2 * NBIN];
    int tid = threadIdx.x;
    int e0 = blockIdx.x * EPB;
    int n = Ee - e0; if (n > EPB) n = EPB;

    for (int i = tid; i < 2 * NBIN; i += 256) hist[i] = 0;
    __syncthreads();
    for (int i = tid; i < n; i += 256) {
        int u = ei[e0 + i], p = ei[Ee + e0 + i];
        atomicAdd(&hist[p >> BSH], 1);
        atomicAdd(&hist[NBIN + (u >> BSH)], 1);
    }
    __syncthreads();
    for (int i = tid; i < 2 * NBIN; i += 256) {
        int c = hist[i];
        base[i] = c ? atomicAdd(&bin_cnt[i], c) : 0;
    }
    __syncthreads();
    for (int i = tid; i < 2 * NBIN; i += 256) hist[i] = base[i];
    __syncthreads();
    for (int i = tid; i < n; i += 256) {
        int u = ei[e0 + i], p = ei[Ee + e0 + i];
        int bp = p >> BSH, bu = u >> BSH;
        int rp = atomicAdd(&hist[bp], 1);
        if (rp < BCAP)
            ent_p[(size_t)bp * BCAP + rp] = ((uint_t)(p & (BINSZ - 1)) << 16) | (uint_t)u;
        int ru = atomicAdd(&hist[NBIN + bu], 1);
        if (ru < BCAP)
            ent_u[(size_t)bu * BCAP + ru] = ((uint_t)(u & (BINSZ - 1)) << 16) | (uint_t)p;
    }
}

__global__ void k_binscan(const int* __restrict__ bin_cnt, int* __restrict__ bin_base) {
    __shared__ int buf[2][128];
    int t = threadIdx.x;
    int side = t >> 7, i = t & 127;
    int v = 0;
    if (i < NBIN) { v = bin_cnt[side * NBIN + i]; if (v > BCAP) v = BCAP; }
    buf[side][i] = v;
    __syncthreads();
    #pragma unroll
    for (int d = 1; d < 128; d <<= 1) {
        int x = (i >= d) ? buf[side][i - d] : 0;
        __syncthreads();
        buf[side][i] += x;
        __syncthreads();
    }
    if (i < NBIN) bin_base[side * NBIN + i] = buf[side][i] - v;
}

__global__ __launch_bounds__(512) void k_scatter(
    const uint_t* __restrict__ ent_p, const uint_t* __restrict__ ent_u,
    const int* __restrict__ bin_cnt, const int* __restrict__ bin_base,
    int* __restrict__ off, int* __restrict__ cnt,
    int* __restrict__ src_p, int* __restrict__ src_u) {
    __shared__ int ca[BINSZ];
    __shared__ int cb[BINSZ];
    int side = blockIdx.y, b = blockIdx.x, t = threadIdx.x;
    const uint_t* E = (side ? ent_u : ent_p) + (size_t)b * BCAP;
    int* src = side ? src_u : src_p;
    int nb = bin_cnt[side * NBIN + b]; if (nb > BCAP) nb = BCAP;
    int base = bin_base[side * NBIN + b];

    ca[t] = 0;
    __syncthreads();
    for (int i = t; i < nb; i += 512)
        atomicAdd(&ca[E[i] >> 16], 1);
    __syncthreads();
    int v = ca[t];
    int* A = ca; int* B = cb;
    #pragma unroll
    for (int d = 1; d < BINSZ; d <<= 1) {
        int x = A[t] + ((t >= d) ? A[t - d] : 0);
        B[t] = x;
        __syncthreads();
        int* tmp = A; A = B; B = tmp;
    }
    int excl = A[t] - v;
    B[t] = excl;
    __syncthreads();
    for (int i = t; i < nb; i += 512) {
        uint_t e = E[i];
        int sl = atomicAdd(&B[e >> 16], 1);
        src[base + sl] = (int)(e & 0xffffu);
    }
    int d = (b << BSH) + t;
    if (d < Nn) {
        off[side * Nn + d] = base + excl;
        cnt[side * Nn + d] = v;
    }
}

// ---------------- layer-1 mean aggregation, both sides, D=128, unroll 8 ----------------
__global__ void k_agg1(const us_t* __restrict__ xu, const us_t* __restrict__ xp,
                       const int* __restrict__ off, const int* __restrict__ cnt,
                       const int* __restrict__ src_p, const int* __restrict__ src_u,
                       us_t* __restrict__ mu, us_t* __restrict__ mp) {
    int side = blockIdx.y;
    const us_t* X = side ? xp : xu;
    const int* of = off + side * Nn;
    const int* cn = cnt + side * Nn;
    const int* sr = side ? src_u : src_p;
    us_t* out = side ? mp : mu;

    int node = blockIdx.x * 4 + (threadIdx.x >> 6);
    if (node >= Nn) return;
    int lane = threadIdx.x & 63;
    int s = of[node], c = cn[node];
    float ax = 0.f, ay = 0.f;
    int j = 0;
    for (; j + 8 <= c; j += 8) {
        int ss[8];
        #pragma unroll
        for (int q = 0; q < 8; ++q) ss[q] = sr[s + j + q];
        uint_t vv[8];
        #pragma unroll
        for (int q = 0; q < 8; ++q)
            vv[q] = reinterpret_cast<const uint_t*>(X + (size_t)ss[q] * 128)[lane];
        #pragma unroll
        for (int q = 0; q < 8; ++q) { ax += bflo(vv[q]); ay += bfhi(vv[q]); }
    }
    for (; j < c; ++j) {
        int s0 = sr[s + j];
        uint_t v0 = reinterpret_cast<const uint_t*>(X + (size_t)s0 * 128)[lane];
        ax += bflo(v0); ay += bfhi(v0);
    }
    float inv = 1.0f / fmaxf((float)c, 1.0f);
    uint_t pack = (uint_t)f2bf(ax * inv) | ((uint_t)f2bf(ay * inv) << 16);
    reinterpret_cast<uint_t*>(out + (size_t)node * 128)[lane] = pack;
}

// ---------------- layer-2 mean aggregation, both sides, D=64, unroll 4 ----------------
__global__ void k_agg2(const us_t* __restrict__ tu, const us_t* __restrict__ tp,
                       const int* __restrict__ off, const int* __restrict__ cnt,
                       const int* __restrict__ src_p, const int* __restrict__ src_u,
                       float* __restrict__ ou, float* __restrict__ op) {
    int side = blockIdx.y;
    const us_t* T = side ? tp : tu;
    const int* of = off + side * Nn;
    const int* cn = cnt + side * Nn;
    const int* sr = side ? src_u : src_p;
    float* out = side ? op : ou;

    int node = blockIdx.x * 16 + (threadIdx.x >> 4);
    if (node >= Nn) return;
    int sl = threadIdx.x & 15;
    int s = of[node], c = cn[node];
    float a0 = 0.f, a1 = 0.f, a2 = 0.f, a3 = 0.f;
    int j = 0;
    for (; j + 4 <= c; j += 4) {
        int ss[4];
        #pragma unroll
        for (int q = 0; q < 4; ++q) ss[q] = sr[s + j + q];
        uint2 vv[4];
        #pragma unroll
        for (int q = 0; q < 4; ++q)
            vv[q] = reinterpret_cast<const uint2*>(T + (size_t)ss[q] * 64)[sl];
        #pragma unroll
        for (int q = 0; q < 4; ++q) {
            a0 += bflo(vv[q].x); a1 += bfhi(vv[q].x);
            a2 += bflo(vv[q].y); a3 += bfhi(vv[q].y);
        }
    }
    for (; j < c; ++j) {
        int s0 = sr[s + j];
        uint2 v0 = reinterpret_cast<const uint2*>(T + (size_t)s0 * 64)[sl];
        a0 += bflo(v0.x); a1 += bfhi(v0.x); a2 += bflo(v0.y); a3 += bfhi(v0.y);
    }
    float inv = 1.0f / fmaxf((float)c, 1.0f);
    float4* o = reinterpret_cast<float4*>(out + (size_t)node * 64) + sl;
    float4 p = *o;
    p.x += a0 * inv; p.y += a1 * inv; p.z += a2 * inv; p.w += a3 * inv;
    *o = p;
}

// ---------------- MFMA GEMM core macros ----------------
#define MM_STAGE(Ap, Wp, K, BN, KSLOT)                                              \
    do {                                                                            \
        _Pragma("unroll")                                                           \
        for (int ii = 0; ii < (64 * KSLOT) / 256; ++ii) {                           \
            int s_ = ii * 256 + tid;                                                \
            int row = s_ / KSLOT, ks = s_ % KSLOT;                                  \
            int ksl = ks ^ (row & 7);                                               \
            int grow = node_base + row; if (grow >= Nn) grow = Nn - 1;              \
            const void* g = (Ap) + (size_t)grow * K + ksl * 8;                      \
            __builtin_amdgcn_global_load_lds(                                       \
                (const __attribute__((address_space(1))) unsigned int*)g,           \
                (__attribute__((address_space(3))) unsigned int*)&sA[(s_ - lane) * 8], \
                16, 0, 0);                                                          \
        }                                                                           \
        _Pragma("unroll")                                                           \
        for (int ii = 0; ii < (BN * KSLOT) / 256; ++ii) {                           \
            int s_ = ii * 256 + tid;                                                \
            int row = s_ / KSLOT, ks = s_ % KSLOT;                                  \
            int ksl = ks ^ (row & 7);                                               \
            const void* g = (Wp) + (size_t)(out_base + row) * K + ksl * 8;          \
            __builtin_amdgcn_global_load_lds(                                       \
                (const __attribute__((address_space(1))) unsigned int*)g,           \
                (__attribute__((address_space(3))) unsigned int*)&sW[(s_ - lane) * 8], \
                16, 0, 0);                                                          \
        }                                                                           \
        asm volatile("s_waitcnt vmcnt(0)" ::: "memory");                            \
        __syncthreads();                                                            \
    } while (0)

#define MM_COMPUTE(K, BN, FN)                                                       \
    do {                                                                            \
        _Pragma("unroll")                                                           \
        for (int ks = 0; ks < K / 32; ++ks) {                                       \
            short8 af[2], bfr[FN];                                                  \
            _Pragma("unroll")                                                       \
            for (int m = 0; m < 2; ++m) {                                           \
                int row = wr * 32 + m * 16 + (lane & 15);                           \
                int ksl = (ks * 4 + (lane >> 4)) ^ (row & 7);                       \
                af[m] = *reinterpret_cast<const short8*>(&sA[row * K + ksl * 8]);   \
            }                                                                       \
            _Pragma("unroll")                                                       \
            for (int n = 0; n < FN; ++n) {                                          \
                int row = wc * (BN / 2) + n * 16 + (lane & 15);                     \
                int ksl = (ks * 4 + (lane >> 4)) ^ (row & 7);                       \
                bfr[n] = *reinterpret_cast<const short8*>(&sW[row * K + ksl * 8]);  \
            }                                                                       \
            _Pragma("unroll")                                                       \
            for (int m = 0; m < 2; ++m)                                             \
                _Pragma("unroll")                                                   \
                for (int n = 0; n < FN; ++n)                                        \
                    acc[m][n] = __builtin_amdgcn_mfma_f32_16x16x32_bf16(            \
                        af[m], bfr[n], acc[m][n], 0, 0, 0);                         \
        }                                                                           \
    } while (0)

// ---------------- layer-1 dual GEMM, both sides: blockIdx.z = job ----------------
// job 0: h_u = relu(mean_u.Wu1l^T + x_p.Wu1r^T + b_u1)
// job 1: h_p = relu(mean_p.Wp1l^T + x_u.Wp1r^T + b_p1)
__global__ __launch_bounds__(256) void k_mm1(
    const us_t* __restrict__ mu, const us_t* __restrict__ mp,
    const us_t* __restrict__ xbu, const us_t* __restrict__ xbp,
    const us_t* __restrict__ wu1l, const us_t* __restrict__ wu1r,
    const us_t* __restrict__ wp1l, const us_t* __restrict__ wp1r,
    const float* __restrict__ bu1, const float* __restrict__ bp1,
    us_t* __restrict__ hu, us_t* __restrict__ hp) {
    constexpr int K = FIN, BN = 128, KSLOT = K / 8, FN = BN / 32;
    __shared__ us_t sA[64 * K];
    __shared__ us_t sW[BN * K];
    int tid = threadIdx.x, lane = tid & 63;
    int w = tid >> 6, wr = w >> 1, wc = w & 1;
    int node_base = blockIdx.x * 64, out_base = blockIdx.y * BN;
    int job = blockIdx.z;

    const us_t* A0 = job ? mp : mu;
    const us_t* A1 = job ? xbu : xbp;
    const us_t* W0 = job ? wp1l : wu1l;
    const us_t* W1 = job ? wp1r : wu1r;
    const float* bias = job ? bp1 : bu1;
    us_t* C = job ? hp : hu;

    f32x4 acc[2][FN];
    #pragma unroll
    for (int m = 0; m < 2; ++m)
        #pragma unroll
        for (int n = 0; n < FN; ++n)
            #pragma unroll
            for (int i = 0; i < 4; ++i) acc[m][n][i] = 0.f;

    MM_STAGE(A0, W0, K, BN, KSLOT);
    MM_COMPUTE(K, BN, FN);
    __syncthreads();
    MM_STAGE(A1, W1, K, BN, KSLOT);
    MM_COMPUTE(K, BN, FN);

    #pragma unroll
    for (int n = 0; n < FN; ++n) {
        int col = out_base + wc * (BN / 2) + n * 16 + (lane & 15);
        float bv = bias[col];
        #pragma unroll
        for (int m = 0; m < 2; ++m) {
            int row0 = node_base + wr * 32 + m * 16 + ((lane >> 4) << 2);
            #pragma unroll
            for (int j = 0; j < 4; ++j) {
                int row = row0 + j;
                if (row >= Nn) continue;
                float v = fmaxf(acc[m][n][j] + bv, 0.f);
                hu[0] = hu[0];  // no-op keep
                C[(size_t)row * HIDD + col] = f2bf(v);
            }
        }
    }
}

// ---------------- layer-2 GEMMs, 4 jobs: blockIdx.z ----------------
// job 0: tu = hu.Wu2l^T (bf16)     job 1: ou = hp.Wu2r^T + b_u2 (f32)
// job 2: tp = hp.Wp2l^T (bf16)     job 3: op = hu.Wp2r^T + b_p2 (f32)
__global__ __launch_bounds__(256) void k_mm2(
    const us_t* __restrict__ hu, const us_t* __restrict__ hp,
    const us_t* __restrict__ wu2l, const us_t* __restrict__ wu2r,
    const us_t* __restrict__ wp2l, const us_t* __restrict__ wp2r,
    const float* __restrict__ bu2, const float* __restrict__ bp2,
    us_t* __restrict__ tu, us_t* __restrict__ tp,
    float* __restrict__ ou, float* __restrict__ op) {
    constexpr int K = HIDD, BN = 64, KSLOT = K / 8, FN = BN / 32;
    __shared__ us_t sA[64 * K];
    __shared__ us_t sW[BN * K];
    int tid = threadIdx.x, lane = tid & 63;
    int w = tid >> 6, wr = w >> 1, wc = w & 1;
    int node_base = blockIdx.x * 64, out_base = 0;
    int job = blockIdx.z;

    const us_t* A; const us_t* W;
    switch (job) {
        case 0: A = hu; W = wu2l; break;
        case 1: A = hp; W = wu2r; break;
        case 2: A = hp; W = wp2l; break;
        default: A = hu; W = wp2r; break;
    }

    f32x4 acc[2][FN];
    #pragma unroll
    for (int m = 0; m < 2; ++m)
        #pragma unroll
        for (int n = 0; n < FN; ++n)
            #pragma unroll
            for (int i = 0; i < 4; ++i) acc[m][n][i] = 0.f;

    MM_STAGE(A, W, K, BN, KSLOT);
    MM_COMPUTE(K, BN, FN);

    #pragma unroll
    for (int n = 0; n < FN; ++n) {
        int col = wc * (BN / 2) + n * 16 + (lane & 15);
        float bv = (job == 1) ? bu2[col] : (job == 3 ? bp2[col] : 0.f);
        #pragma unroll
        for (int m = 0; m < 2; ++m) {
            int row0 = node_base + wr * 32 + m * 16 + ((lane >> 4) << 2);
            #pragma unroll
            for (int j = 0; j < 4; ++j) {
                int row = row0 + j;
                if (row >= Nn) continue;
                float v = acc[m][n][j] + bv;
                if (job == 0)       tu[(size_t)row * CLSS + col] = f2bf(v);
                else if (job == 2)  tp[(size_t)row * CLSS + col] = f2bf(v);
                else if (job == 1)  ou[(size_t)row * CLSS + col] = v;
                else                op[(size_t)row * CLSS + col] = v;
            }
        }
    }
}

// ---------------- launch ----------------
extern "C" void kernel_launch(void* const* d_in, const int* in_sizes, int n_in,
                              void* d_out, int out_size, void* d_ws, size_t ws_size,
                              hipStream_t stream) {
    const float* x_user    = (const float*)d_in[0];
    const float* x_product = (const float*)d_in[1];
    const int*   ei        = (const int*)d_in[2];
    const float* w_u1_l = (const float*)d_in[3];
    const float* b_u1   = (const float*)d_in[4];
    const float* w_u1_r = (const float*)d_in[5];
    const float* w_p1_l = (const float*)d_in[6];
    const float* b_p1   = (const float*)d_in[7];
    const float* w_p1_r = (const float*)d_in[8];
    const float* w_u2_l = (const float*)d_in[9];
    const float* b_u2   = (const float*)d_in[10];
    const float* w_u2_r = (const float*)d_in[11];
    const float* w_p2_l = (const float*)d_in[12];
    const float* b_p2   = (const float*)d_in[13];
    const float* w_p2_r = (const float*)d_in[14];

    float* out_u = (float*)d_out;
    float* out_p = out_u + (size_t)Nn * CLSS;

    char* w = (char*)d_ws;
    int* bin_cnt  = (int*)w; w += (size_t)2 * NBIN * 4;
    int* bin_base = (int*)w; w += (size_t)2 * NBIN * 4;
    int* off  = (int*)w;  w += (size_t)2 * Nn * 4;
    int* cnt  = (int*)w;  w += (size_t)2 * Nn * 4;
    int* src_p = (int*)w; w += (size_t)Ee * 4;
    int* src_u = (int*)w; w += (size_t)Ee * 4;
    uint_t* ent_p = (uint_t*)w; w += (size_t)NBIN * BCAP * 4;
    uint_t* ent_u = (uint_t*)w; w += (size_t)NBIN * BCAP * 4;
    uintptr_t a = (uintptr_t)w; a = (a + 255) & ~(uintptr_t)255; w = (char*)a;
    us_t* xbu  = (us_t*)w; w += (size_t)Nn * FIN * 2;
    us_t* xbp  = (us_t*)w; w += (size_t)Nn * FIN * 2;
    us_t* h_u  = (us_t*)w; w += (size_t)Nn * HIDD * 2;
    us_t* h_p  = (us_t*)w; w += (size_t)Nn * HIDD * 2;
    us_t* mean_u = (us_t*)w; w += (size_t)Nn * FIN * 2;
    us_t* mean_p = (us_t*)w; w += (size_t)Nn * FIN * 2;
    us_t* tbuf_u = (us_t*)w; w += (size_t)Nn * CLSS * 2;
    us_t* tbuf_p = (us_t*)w; w += (size_t)Nn * CLSS * 2;
    us_t* wb_u1l = (us_t*)w; w += (size_t)HIDD * FIN * 2;
    us_t* wb_u1r = (us_t*)w; w += (size_t)HIDD * FIN * 2;
    us_t* wb_p1l = (us_t*)w; w += (size_t)HIDD * FIN * 2;
    us_t* wb_p1r = (us_t*)w; w += (size_t)HIDD * FIN * 2;
    us_t* wb_u2l = (us_t*)w; w += (size_t)CLSS * HIDD * 2;
    us_t* wb_u2r = (us_t*)w; w += (size_t)CLSS * HIDD * 2;
    us_t* wb_p2l = (us_t*)w; w += (size_t)CLSS * HIDD * 2;
    us_t* wb_p2r = (us_t*)w; w += (size_t)CLSS * HIDD * 2;

    // conversions + bin_cnt zero
    {
        int n4 = (Nn * FIN) / 4;
        int blocks = (n4 + 255) / 256; if (blocks > 1024) blocks = 1024;
        dim3 g(blocks, 2);
        k_cvtx<<<g, 256, 0, stream>>>(x_user, x_product, xbu, xbp, n4);
    }
    k_cvtw<<<193, 256, 0, stream>>>(w_u1_l, w_u1_r, w_p1_l, w_p1_r,
                                    w_u2_l, w_u2_r, w_p2_l, w_p2_r,
                                    wb_u1l, wb_u1r, wb_p1l, wb_p1r,
                                    wb_u2l, wb_u2r, wb_p2l, wb_p2r, bin_cnt);

    // binned CSR build
    k_bin<<<NEB, 256, 0, stream>>>(ei, bin_cnt, ent_p, ent_u);
    k_binscan<<<1, 256, 0, stream>>>(bin_cnt, bin_base);
    dim3 gsc(NBIN, 2);
    k_scatter<<<gsc, 512, 0, stream>>>(ent_p, ent_u, bin_cnt, bin_base,
                                       off, cnt, src_p, src_u);

    // ---- layer 1 ----
    dim3 ga1((Nn + 3) / 4, 2);
    k_agg1<<<ga1, 256, 0, stream>>>(xbu, xbp, off, cnt, src_p, src_u, mean_u, mean_p);
    dim3 g1((Nn + 63) / 64, HIDD / 128, 2);
    k_mm1<<<g1, 256, 0, stream>>>(mean_u, mean_p, xbu, xbp,
                                  wb_u1l, wb_u1r, wb_p1l, wb_p1r,
                                  b_u1, b_p1, h_u, h_p);

    // ---- layer 2 ----
    dim3 g2((Nn + 63) / 64, 1, 4);
    k_mm2<<<g2, 256, 0, stream>>>(h_u, h_p, wb_u2l, wb_u2r, wb_p2l, wb_p2r,
                                  b_u2, b_p2, tbuf_u, tbuf_p, out_u, out_p);
    dim3 ga2((Nn + 15) / 16, 2);
    k_agg2<<<ga2, 256, 0, stream>>>(tbuf_u, tbuf_p, off, cnt, src_p, src_u, out_u, out_p);
}